// Round 5
// baseline (174.807 us; speedup 1.0000x reference)
//
#include <hip/hip_runtime.h>
#include <hip/hip_bf16.h>
#include <stdint.h>

#define B_ 8
#define L_ 2048
#define NTOK 16384      // B_*L_
#define DK 256          // K (input dim)
#define DM 1024         // N (d_model)
#define NS 16           // num signals
#define LOUT 2049
#define TOK_OUT (B_*LOUT*DM)   // 16785408
#define ATTN_OUT (B_*LOUT)     // 16392
#define PCAP 2048       // per-signal perm region (mean 768, sd ~27)

typedef unsigned short u16;
typedef unsigned int u32;
typedef __bf16 bf16x8 __attribute__((ext_vector_type(8)));
typedef float f32x4 __attribute__((ext_vector_type(4)));

// pack two fp32 -> two bf16 (round-to-nearest-up via +0x8000; data ~N(0,1))
__device__ inline u32 packbf2(float lo, float hi) {
    u32 a, b;
    __builtin_memcpy(&a, &lo, 4);
    __builtin_memcpy(&b, &hi, 4);
    a = (a + 0x8000u) >> 16;
    b = (b + 0x8000u) & 0xFFFF0000u;
    return a | b;
}

__device__ inline void gll16(const void* g, void* l) {
    __builtin_amdgcn_global_load_lds(
        (const __attribute__((address_space(1))) unsigned int*)g,
        (__attribute__((address_space(3))) unsigned int*)l, 16, 0, 0);
}

// ws layout (ints):
//   [0..16)   WS_CUR  signal counts (atomic cursors; final = counts)
//   [64..64+NS*PCAP)          perm, fixed regions of PCAP per signal
//   [64+NS*PCAP .. +NTOK)     mask (0/1)
// bytes:
//   A_OFF: A_bf16, 18432 rows x 256 bf16 (perm-gathered, per-signal pad->128)
//   W_OFF: W_bf16, 16384 rows x 256 bf16
#define WS_CUR 0
#define WS_PERM 64
#define WS_MASK (64 + NS * PCAP)                                  // 32832
#define A_OFF 262144ULL
#define APAD_ROWS 18432
#define W_OFF (A_OFF + (unsigned long long)APAD_ROWS * 512ULL)    // 9,699,328
#define WS_NEED (W_OFF + 16384ULL * 512ULL)                       // 18,087,936

// ---------------- Sort: mask decode + counting scatter (one kernel) ----------
__global__ __launch_bounds__(256) void sort_kernel(const unsigned char* __restrict__ mb,
                                                   const int* __restrict__ sid,
                                                   int* __restrict__ wsi) {
    __shared__ int f_c1ge2, f_ge2, f_odd;
    __shared__ int lcnt[NS], gbase[NS];
    int tid = threadIdx.x;
    if (tid == 0) { f_c1ge2 = 0; f_ge2 = 0; f_odd = 0; }
    if (tid < NS) lcnt[tid] = 0;
    __syncthreads();

    // width sniff over first 16 KB (valid for any elem width >= 1B)
    int c1ge2 = 0, ge2 = 0, oddnz = 0;
    const u32* mw = (const u32*)mb;
    #pragma unroll
    for (int i = 0; i < 16; i++) {
        u32 x = mw[tid * 16 + i];
        u32 b0 = x & 0xFF, b1 = (x >> 8) & 0xFF, b2 = (x >> 16) & 0xFF, b3 = x >> 24;
        if (b1 >= 2) c1ge2 = 1;
        if (b0 >= 2 || b1 >= 2 || b2 >= 2 || b3 >= 2) ge2 = 1;
        if ((b1 | b3) != 0) oddnz = 1;
    }
    if (c1ge2) atomicOr(&f_c1ge2, 1);
    if (ge2) atomicOr(&f_ge2, 1);
    if (oddnz) atomicOr(&f_odd, 1);
    __syncthreads();

    int width;
    if (f_c1ge2) width = 2;
    else if (f_ge2) width = 4;
    else if (f_odd) width = 1;
    else width = 4;

    int t = blockIdx.x * 256 + tid;
    int m;
    if (width == 1) m = (mb[t] != 0);
    else if (width == 2) m = (((const u16*)mb)[t] != 0);
    else m = (((const u32*)mb)[t] != 0);

    wsi[WS_MASK + t] = m;
    int s = sid[t];
    int lr = 0;
    if (m) lr = atomicAdd(&lcnt[s], 1);
    __syncthreads();
    if (tid < NS) gbase[tid] = atomicAdd(&wsi[WS_CUR + tid], lcnt[tid]);
    __syncthreads();
    if (m) {
        int r = gbase[s] + lr;
        if (r < PCAP) wsi[WS_PERM + s * PCAP + r] = t;
    }
}

// ---------------- Prep: build sorted-padded A_bf16 + W_bf16 ------------------
__global__ __launch_bounds__(256) void prep_kernel(const float* __restrict__ emb,
                                                   const float* __restrict__ W,
                                                   const int* __restrict__ wsi,
                                                   unsigned char* __restrict__ wsb) {
    int bid = blockIdx.x;
    int tid = threadIdx.x;
    int lane = tid & 63;
    int wv = tid >> 6;
    if (bid < 4608) {
        int cnts[NS], segoff[NS];
        int accp = 0;
        #pragma unroll
        for (int i = 0; i < NS; i++) {
            int c = wsi[WS_CUR + i];
            cnts[i] = c > PCAP ? PCAP : c;
            segoff[i] = accp;
            accp += ((cnts[i] + 127) >> 7) << 7;
        }
        int r = bid * 4 + wv;
        if (r >= accp) return;
        int s = 0;
        #pragma unroll
        for (int i = 1; i < NS; i++) if (r >= segoff[i]) s = i;
        int local = r - segoff[s];
        u16* Ab = (u16*)(wsb + A_OFF);
        uint2 o;
        if (local < cnts[s]) {
            int t = wsi[WS_PERM + s * PCAP + local];
            float4 a = *(const float4*)(emb + (size_t)t * DK + lane * 4);
            o.x = packbf2(a.x, a.y);
            o.y = packbf2(a.z, a.w);
        } else {
            o.x = 0; o.y = 0;
        }
        *(uint2*)(Ab + (size_t)r * DK + lane * 4) = o;
    } else {
        int r = (bid - 4608) * 4 + wv;   // 0..16383 = s*1024 + n
        u16* Wb = (u16*)(wsb + W_OFF);
        float4 a = *(const float4*)(W + (size_t)r * DK + lane * 4);
        uint2 o;
        o.x = packbf2(a.x, a.y);
        o.y = packbf2(a.z, a.w);
        *(uint2*)(Wb + (size_t)r * DK + lane * 4) = o;
    }
}

// ---------------- Persistent grouped GEMM 128(M)x256(N), BK=32, dbuf ---------
// 256 blocks (1/CU, enforced via LDS padding), task loop with cross-task
// software pipeline: at last chunk of task t, chunk 0 of task t+1 is issued;
// the epilogue of t hides its latency.
// LDS rows: 32 bf16 = 64 B = 4 segs of 16B. Swizzle: LDS(row, seg) holds
// global seg (seg - (row>>1)) & 3, frag read seg = (quad + (row>>1)) & 3.
struct Desc {
    const u16* Ab;
    const u16* Bb;
    int s, rv, n0, pidx;
};

__global__ __launch_bounds__(512, 2) void gemm_big(
    const int* __restrict__ pos, const int* __restrict__ role,
    const float* __restrict__ bias,
    const float* __restrict__ pos_emb, const float* __restrict__ id_emb,
    const float* __restrict__ role_emb,
    const int* __restrict__ wsi, const unsigned char* __restrict__ wsb,
    float* __restrict__ out) {
    __shared__ u16 As[2][128 * 32];       // 8 KB x2
    __shared__ u16 Bs[2][256 * 32];       // 16 KB x2
    __shared__ int toksbuf[2][128];
    __shared__ int lds_pad[16384];        // 64 KB: forces 1 block/CU

    int tid = threadIdx.x;
    int lane = tid & 63;
    int wv = tid >> 6;               // 0..7

    int cnts[NS];
    int mtot = 0;
    #pragma unroll
    for (int i = 0; i < NS; i++) {
        int c = wsi[WS_CUR + i];
        cnts[i] = c > PCAP ? PCAP : c;
        mtot += (cnts[i] + 127) >> 7;
    }
    if (cnts[0] == -1) ((volatile int*)lds_pad)[0] = 0;   // keep lds_pad live
    int ntasks = mtot * 4;
    int task = (int)blockIdx.x;
    if (task >= ntasks) return;

    const u16* Abase = (const u16*)(wsb + A_OFF);
    const u16* Bbase = (const u16*)(wsb + W_OFF);

#define MKDESC(D, tk)                                                          \
    {                                                                          \
        int m = (tk) >> 2;                                                     \
        D.n0 = ((tk) & 3) << 8;                                                \
        int s_ = -1, lrt_ = 0, seg0_ = 0, accp_ = 0;                           \
        _Pragma("unroll")                                                      \
        for (int i_ = 0; i_ < NS; i_++) {                                      \
            int rt_ = (cnts[i_] + 127) >> 7;                                   \
            if (s_ < 0) {                                                      \
                if (m < rt_) { s_ = i_; lrt_ = m; seg0_ = accp_; }             \
                else m -= rt_;                                                 \
            }                                                                  \
            accp_ += rt_ << 7;                                                 \
        }                                                                      \
        D.s = s_;                                                              \
        int rv_ = cnts[s_] - lrt_ * 128;                                       \
        D.rv = rv_ > 128 ? 128 : rv_;                                          \
        D.pidx = s_ * PCAP + lrt_ * 128;                                       \
        D.Ab = Abase + (size_t)(seg0_ + lrt_ * 128) * DK;                      \
        D.Bb = Bbase + (size_t)(D.s * DM + D.n0) * DK;                         \
    }

    // staging lane map: 16 rows x 4 segs per wave-KB; gll dest = base + lane*16B
    int srow = lane >> 2;
    int slseg = lane & 3;

#define STAGE(D, kc, bf)                                                       \
    {                                                                          \
        int arow = wv * 16 + srow;                                             \
        int ags = (slseg - (arow >> 1)) & 3;                                   \
        gll16(D.Ab + (size_t)arow * DK + (kc) * 32 + ags * 8,                  \
              &As[bf][wv * 16 * 32]);                                          \
        int bgs0 = ags;                                                        \
        gll16(D.Bb + (size_t)arow * DK + (kc) * 32 + bgs0 * 8,                 \
              &Bs[bf][wv * 16 * 32]);                                          \
        int brow1 = 128 + arow;                                                \
        int bgs1 = (slseg - (brow1 >> 1)) & 3;                                 \
        gll16(D.Bb + (size_t)brow1 * DK + (kc) * 32 + bgs1 * 8,                \
              &Bs[bf][(128 + wv * 16) * 32]);                                  \
    }

    Desc d;
    MKDESC(d, task)
    if (tid < 128) toksbuf[0][tid] = (tid < d.rv) ? wsi[WS_PERM + d.pidx + tid] : -1;

    int wm = wv & 1, wn = wv >> 1;   // wave quadrant: 64 rows x 64 cols
    int mcol = lane & 15;
    int quad = lane >> 4;

    int buf = 0, tp = 0;
    STAGE(d, 0, 0)

    while (true) {
        f32x4 acc[4][4];
        #pragma unroll
        for (int im = 0; im < 4; im++)
            #pragma unroll
            for (int jn = 0; jn < 4; jn++) acc[im][jn] = (f32x4){0.f, 0.f, 0.f, 0.f};

        int ntask = task + 256;
        bool have = ntask < ntasks;
        Desc nd = d;

        #pragma unroll
        for (int kc = 0; kc < 8; ++kc) {
            __syncthreads();
            int nb = buf ^ 1;
            if (kc < 7) {
                STAGE(d, kc + 1, nb)
            } else if (have) {
                MKDESC(nd, ntask)
                STAGE(nd, 0, nb)
            }
            bf16x8 af[4], bfr[4];
            #pragma unroll
            for (int im = 0; im < 4; im++) {
                int row = wm * 64 + im * 16 + mcol;
                int sg = (quad + (row >> 1)) & 3;
                af[im] = *(const bf16x8*)(&As[buf][row * 32 + sg * 8]);
            }
            #pragma unroll
            for (int jn = 0; jn < 4; jn++) {
                int row = wn * 64 + jn * 16 + mcol;
                int sg = (quad + (row >> 1)) & 3;
                bfr[jn] = *(const bf16x8*)(&Bs[buf][row * 32 + sg * 8]);
            }
            #pragma unroll
            for (int im = 0; im < 4; im++)
                #pragma unroll
                for (int jn = 0; jn < 4; jn++)
                    acc[im][jn] = __builtin_amdgcn_mfma_f32_16x16x32_bf16(
                        af[im], bfr[jn], acc[im][jn], 0, 0, 0);
            buf = nb;
        }

        // load next task's token ids (visible after next task's 8 barriers)
        if (have && tid < 128)
            toksbuf[tp ^ 1][tid] = (tid < nd.rv) ? wsi[WS_PERM + nd.pidx + tid] : -1;

        // epilogue: row = wm*64+im*16+quad*4+r, col = n0+wn*64+jn*16+mcol
        float bc[4];
        #pragma unroll
        for (int jn = 0; jn < 4; jn++) {
            int col = d.n0 + wn * 64 + jn * 16 + mcol;
            bc[jn] = bias[d.s * DM + col] + id_emb[d.s * DM + col];
        }
        #pragma unroll
        for (int im = 0; im < 4; im++) {
            #pragma unroll
            for (int r = 0; r < 4; r++) {
                int rowT = wm * 64 + im * 16 + quad * 4 + r;
                if (rowT >= d.rv) continue;
                int t = toksbuf[tp][rowT];
                int p = pos[t];
                int ro = role[t];
                int b = t >> 11, l = t & 2047;
                size_t orow = (size_t)(b * LOUT + l + 1) * DM;
                #pragma unroll
                for (int jn = 0; jn < 4; jn++) {
                    int col = d.n0 + wn * 64 + jn * 16 + mcol;
                    float val = acc[im][jn][r] + bc[jn]
                        + pos_emb[(size_t)p * DM + col]
                        + role_emb[ro * DM + col];
                    out[orow + col] = val;
                }
            }
        }
        if (!have) return;
        d = nd;
        task = ntask;
        tp ^= 1;
    }
#undef STAGE
#undef MKDESC
}

// ---------------- Elementwise: unmasked rows (wave/token), CLS, attn ---------
__global__ __launch_bounds__(256) void ew_kernel(
    const int* __restrict__ pos, const int* __restrict__ sid,
    const int* __restrict__ role,
    const float* __restrict__ cls, const float* __restrict__ pos_emb,
    const float* __restrict__ id_emb, const float* __restrict__ role_emb,
    const int* __restrict__ wsi, float* __restrict__ out) {
    int bi = blockIdx.x;
    int tid = threadIdx.x;
    int lane = tid & 63;
    int wv = tid >> 6;
    if (bi < NTOK / 4) {
        int t = bi * 4 + wv;
        if (wsi[WS_MASK + t]) return;   // projected rows written by GEMM
        int p = pos[t], sd = sid[t], ro = role[t];
        int b = t >> 11, l = t & 2047;
        size_t orow = (size_t)(b * LOUT + l + 1) * DM;
        #pragma unroll
        for (int it = 0; it < 4; it++) {
            int c = it * 256 + lane * 4;
            float4 a = *(const float4*)(pos_emb + (size_t)p * DM + c);
            float4 d = *(const float4*)(id_emb + (size_t)sd * DM + c);
            float4 e = *(const float4*)(role_emb + (size_t)ro * DM + c);
            float4 o;
            o.x = a.x + d.x + e.x;
            o.y = a.y + d.y + e.y;
            o.z = a.z + d.z + e.z;
            o.w = a.w + d.w + e.w;
            *(float4*)(out + orow + c) = o;
        }
    } else if (bi < NTOK / 4 + 2) {
        int b = (bi - NTOK / 4) * 4 + wv;   // 8 CLS rows over 2 blocks
        size_t orow = (size_t)(b * LOUT) * DM;
        #pragma unroll
        for (int it = 0; it < 4; it++) {
            int c = it * 256 + lane * 4;
            float4 cc = *(const float4*)(cls + c);
            float4 a = *(const float4*)(pos_emb + c);            // pos row 0
            float4 d = *(const float4*)(id_emb + NS * DM + c);   // id row 16
            float4 e = *(const float4*)(role_emb + 2 * DM + c);  // role 2
            float4 o;
            o.x = cc.x + a.x + d.x + e.x;
            o.y = cc.y + a.y + d.y + e.y;
            o.z = cc.z + a.z + d.z + e.z;
            o.w = cc.w + a.w + d.w + e.w;
            *(float4*)(out + orow + c) = o;
        }
    } else {
        int i = (bi - NTOK / 4 - 2) * 256 + tid;
        if (i < ATTN_OUT) {
            int b = i / LOUT;
            int j = i - b * LOUT;
            float val = (j == 0) ? 1.0f : (float)wsi[WS_MASK + b * L_ + j - 1];
            out[TOK_OUT + i] = val;
        }
    }
}

extern "C" void kernel_launch(void* const* d_in, const int* in_sizes, int n_in,
                              void* d_out, int out_size, void* d_ws, size_t ws_size,
                              hipStream_t stream) {
    const float* emb = (const float*)d_in[0];
    const int* pos = (const int*)d_in[1];
    const int* sid = (const int*)d_in[2];
    const int* role = (const int*)d_in[3];
    const unsigned char* mask = (const unsigned char*)d_in[4];
    const float* W = (const float*)d_in[5];
    const float* bias = (const float*)d_in[6];
    const float* cls = (const float*)d_in[7];
    const float* pos_emb = (const float*)d_in[8];
    const float* id_emb = (const float*)d_in[9];
    const float* role_emb = (const float*)d_in[10];
    float* out = (float*)d_out;
    int* wsi = (int*)d_ws;
    unsigned char* wsb = (unsigned char*)d_ws;

    hipMemsetAsync(wsi, 0, 64 * sizeof(int), stream);
    hipLaunchKernelGGL(sort_kernel, dim3(64), dim3(256), 0, stream, mask, sid, wsi);
    hipLaunchKernelGGL(prep_kernel, dim3(4608 + 4096), dim3(256), 0, stream,
                       emb, W, wsi, wsb);
    hipLaunchKernelGGL(gemm_big, dim3(256), dim3(512), 0, stream,
                       pos, role, bias, pos_emb, id_emb, role_emb, wsi, wsb, out);
    hipLaunchKernelGGL(ew_kernel, dim3(NTOK / 4 + 2 + 65), dim3(256), 0, stream,
                       pos, sid, role, cls, pos_emb, id_emb, role_emb, wsi, out);
}

// Round 6
// 155.488 us; speedup vs baseline: 1.1242x; 1.1242x over previous
//
#include <hip/hip_runtime.h>
#include <hip/hip_bf16.h>
#include <stdint.h>

#define B_ 8
#define L_ 2048
#define NTOK 16384      // B_*L_
#define DK 256          // K (input dim)
#define DM 1024         // N (d_model)
#define NS 16           // num signals
#define LOUT 2049
#define TOK_OUT (B_*LOUT*DM)   // 16785408
#define ATTN_OUT (B_*LOUT)     // 16392
#define PCAP 2048       // per-signal perm region (mean 768, sd ~27)

typedef unsigned short u16;
typedef unsigned int u32;
typedef __bf16 bf16x8 __attribute__((ext_vector_type(8)));
typedef float f32x4 __attribute__((ext_vector_type(4)));

__device__ inline float bf2f(u16 u) {
    u32 x = ((u32)u) << 16;
    float f;
    __builtin_memcpy(&f, &x, 4);
    return f;
}

// pack two fp32 -> two bf16 (round-to-nearest-up via +0x8000; data ~N(0,1))
__device__ inline u32 packbf2(float lo, float hi) {
    u32 a, b;
    __builtin_memcpy(&a, &lo, 4);
    __builtin_memcpy(&b, &hi, 4);
    a = (a + 0x8000u) >> 16;
    b = (b + 0x8000u) & 0xFFFF0000u;
    return a | b;
}

__device__ inline void gll16(const void* g, void* l) {
    __builtin_amdgcn_global_load_lds(
        (const __attribute__((address_space(1))) unsigned int*)g,
        (__attribute__((address_space(3))) unsigned int*)l, 16, 0, 0);
}

// ws layout (ints):
//   [0..16)   WS_CUR  signal counts (atomic cursors; final = counts)
//   [64..64+NS*PCAP)          perm, fixed regions of PCAP per signal
//   [64+NS*PCAP .. +NTOK)     mask (0/1)
// bytes:
//   A_OFF : A_bf16, 18432 rows x 256 bf16 (perm-gathered, per-signal pad->128)
//   W_OFF : W_bf16, 16384 rows x 256 bf16
//   PE_OFF: pos_emb bf16, 4097 rows x 1024
#define WS_CUR 0
#define WS_PERM 64
#define WS_MASK (64 + NS * PCAP)                                  // 32832
#define A_OFF 262144ULL
#define APAD_ROWS 18432
#define W_OFF (A_OFF + (unsigned long long)APAD_ROWS * 512ULL)    // 9,699,328
#define PE_OFF (W_OFF + 16384ULL * 512ULL)                        // 18,087,936
#define WS_NEED (PE_OFF + 4097ULL * 1024ULL * 2ULL)               // 26,478,592

// ---------------- Sort: mask decode + counting scatter (one kernel) ----------
__global__ __launch_bounds__(256) void sort_kernel(const unsigned char* __restrict__ mb,
                                                   const int* __restrict__ sid,
                                                   int* __restrict__ wsi) {
    __shared__ int f_c1ge2, f_ge2, f_odd;
    __shared__ int lcnt[NS], gbase[NS];
    int tid = threadIdx.x;
    if (tid == 0) { f_c1ge2 = 0; f_ge2 = 0; f_odd = 0; }
    if (tid < NS) lcnt[tid] = 0;
    __syncthreads();

    // width sniff over first 16 KB (valid for any elem width >= 1B)
    int c1ge2 = 0, ge2 = 0, oddnz = 0;
    const u32* mw = (const u32*)mb;
    #pragma unroll
    for (int i = 0; i < 16; i++) {
        u32 x = mw[tid * 16 + i];
        u32 b0 = x & 0xFF, b1 = (x >> 8) & 0xFF, b2 = (x >> 16) & 0xFF, b3 = x >> 24;
        if (b1 >= 2) c1ge2 = 1;
        if (b0 >= 2 || b1 >= 2 || b2 >= 2 || b3 >= 2) ge2 = 1;
        if ((b1 | b3) != 0) oddnz = 1;
    }
    if (c1ge2) atomicOr(&f_c1ge2, 1);
    if (ge2) atomicOr(&f_ge2, 1);
    if (oddnz) atomicOr(&f_odd, 1);
    __syncthreads();

    int width;
    if (f_c1ge2) width = 2;
    else if (f_ge2) width = 4;
    else if (f_odd) width = 1;
    else width = 4;

    int t = blockIdx.x * 256 + tid;
    int m;
    if (width == 1) m = (mb[t] != 0);
    else if (width == 2) m = (((const u16*)mb)[t] != 0);
    else m = (((const u32*)mb)[t] != 0);

    wsi[WS_MASK + t] = m;
    int s = sid[t];
    int lr = 0;
    if (m) lr = atomicAdd(&lcnt[s], 1);
    __syncthreads();
    if (tid < NS) gbase[tid] = atomicAdd(&wsi[WS_CUR + tid], lcnt[tid]);
    __syncthreads();
    if (m) {
        int r = gbase[s] + lr;
        if (r < PCAP) wsi[WS_PERM + s * PCAP + r] = t;
    }
}

// ---------------- Prep: A_bf16 + W_bf16 + pos_emb_bf16 -----------------------
__global__ __launch_bounds__(256) void prep_kernel(const float* __restrict__ emb,
                                                   const float* __restrict__ W,
                                                   const float* __restrict__ pos_emb,
                                                   const int* __restrict__ wsi,
                                                   unsigned char* __restrict__ wsb) {
    int bid = blockIdx.x;
    int tid = threadIdx.x;
    int lane = tid & 63;
    int wv = tid >> 6;
    if (bid < 4608) {
        int cnts[NS], segoff[NS];
        int accp = 0;
        #pragma unroll
        for (int i = 0; i < NS; i++) {
            int c = wsi[WS_CUR + i];
            cnts[i] = c > PCAP ? PCAP : c;
            segoff[i] = accp;
            accp += ((cnts[i] + 127) >> 7) << 7;
        }
        int r = bid * 4 + wv;
        if (r >= accp) return;
        int s = 0;
        #pragma unroll
        for (int i = 1; i < NS; i++) if (r >= segoff[i]) s = i;
        int local = r - segoff[s];
        u16* Ab = (u16*)(wsb + A_OFF);
        uint2 o;
        if (local < cnts[s]) {
            int t = wsi[WS_PERM + s * PCAP + local];
            float4 a = *(const float4*)(emb + (size_t)t * DK + lane * 4);
            o.x = packbf2(a.x, a.y);
            o.y = packbf2(a.z, a.w);
        } else {
            o.x = 0; o.y = 0;
        }
        *(uint2*)(Ab + (size_t)r * DK + lane * 4) = o;
    } else if (bid < 4608 + 4096) {
        int r = (bid - 4608) * 4 + wv;   // 0..16383 = s*1024 + n
        u16* Wb = (u16*)(wsb + W_OFF);
        float4 a = *(const float4*)(W + (size_t)r * DK + lane * 4);
        uint2 o;
        o.x = packbf2(a.x, a.y);
        o.y = packbf2(a.z, a.w);
        *(uint2*)(Wb + (size_t)r * DK + lane * 4) = o;
    } else {
        int r = bid - (4608 + 4096);     // pos_emb row 0..4096
        u16* Pb = (u16*)(wsb + PE_OFF);
        int c = tid * 4;
        float4 a = *(const float4*)(pos_emb + (size_t)r * DM + c);
        uint2 o;
        o.x = packbf2(a.x, a.y);
        o.y = packbf2(a.z, a.w);
        *(uint2*)(Pb + (size_t)r * DM + c) = o;
    }
}

// ---------------- Grouped GEMM 128(M)x256(N), BK=32, dbuf, XCD-partitioned ---
// Task map: xcd = blockIdx.x & 7 owns m-tiles [xcd*mtot/8, (xcd+1)*mtot/8);
// within an XCD tasks are n-major so A m-tiles (4x reuse) and W slabs
// (~6x reuse per signal) stay in that XCD's L2.
// LDS rows: 32 bf16 = 64 B = 4 segs of 16B. Swizzle: LDS(row, seg) holds
// global seg (seg - (row>>1)) & 3, frag read seg = (quad + (row>>1)) & 3.
__global__ __launch_bounds__(512, 4) void gemm_big(
    const int* __restrict__ pos, const int* __restrict__ role,
    const float* __restrict__ bias,
    const float* __restrict__ id_emb, const float* __restrict__ role_emb,
    const int* __restrict__ wsi, const unsigned char* __restrict__ wsb,
    float* __restrict__ out) {
    __shared__ u16 As[2][128 * 32];   // 8 KB x2
    __shared__ u16 Bs[2][256 * 32];   // 16 KB x2
    __shared__ int toks[128];
    int tid = threadIdx.x;
    int lane = tid & 63;
    int wv = tid >> 6;               // 0..7

    int cnts[NS];
    int mtot = 0;
    #pragma unroll
    for (int i = 0; i < NS; i++) {
        int c = wsi[WS_CUR + i];
        cnts[i] = c > PCAP ? PCAP : c;
        mtot += (cnts[i] + 127) >> 7;
    }
    // XCD-partitioned task decode
    int bi = (int)blockIdx.x;
    int xcd = bi & 7;
    int j = bi >> 3;                  // slot within XCD, 0..71
    int m_lo = (xcd * mtot) >> 3;
    int m_hi = ((xcd + 1) * mtot) >> 3;
    int cm = m_hi - m_lo;
    if (cm <= 0 || j >= cm * 4) return;
    int nt = j / cm;                  // n-major within XCD
    int m = m_lo + (j - nt * cm);
    int n0 = nt << 8;

    int s = -1, lrt = 0, seg0 = 0;
    {
        int accp = 0;
        #pragma unroll
        for (int i = 0; i < NS; i++) {
            int rt = (cnts[i] + 127) >> 7;
            if (s < 0) {
                if (m < rt) { s = i; lrt = m; seg0 = accp; }
                else m -= rt;
            }
            accp += rt << 7;
        }
    }
    if (s < 0) return;
    int rowsValid = cnts[s] - lrt * 128;
    if (rowsValid > 128) rowsValid = 128;

    if (tid < 128) toks[tid] = (tid < rowsValid) ? wsi[WS_PERM + s * PCAP + lrt * 128 + tid] : -1;

    const u16* Ab = (const u16*)(wsb + A_OFF) + (size_t)(seg0 + lrt * 128) * DK;
    const u16* Bb = (const u16*)(wsb + W_OFF) + (size_t)(s * DM + n0) * DK;
    const u16* Pb = (const u16*)(wsb + PE_OFF);

    // staging lane map: 16 rows x 4 segs per wave-KB; LDS off = lane*8 elems
    int srow = lane >> 2;
    int slseg = lane & 3;

    f32x4 acc[4][4];
    #pragma unroll
    for (int im = 0; im < 4; im++)
        #pragma unroll
        for (int jn = 0; jn < 4; jn++) acc[im][jn] = (f32x4){0.f, 0.f, 0.f, 0.f};

    int wm = wv & 1, wn = wv >> 1;   // wave quadrant: 64 rows x 64 cols
    int mcol = lane & 15;
    int quad = lane >> 4;

#define STAGE(kc, bf)                                                          \
    {                                                                          \
        int arow = wv * 16 + srow;                                             \
        int ags = (slseg - (arow >> 1)) & 3;                                   \
        gll16(Ab + (size_t)arow * DK + (kc) * 32 + ags * 8,                    \
              &As[bf][wv * 16 * 32]);                                          \
        gll16(Bb + (size_t)arow * DK + (kc) * 32 + ags * 8,                    \
              &Bs[bf][wv * 16 * 32]);                                          \
        int brow1 = 128 + arow;                                                \
        int bgs1 = (slseg - (brow1 >> 1)) & 3;                                 \
        gll16(Bb + (size_t)brow1 * DK + (kc) * 32 + bgs1 * 8,                  \
              &Bs[bf][(128 + wv * 16) * 32]);                                  \
    }

    STAGE(0, 0)
    #pragma unroll
    for (int kc = 0; kc < 8; ++kc) {
        __syncthreads();
        if (kc < 7) STAGE(kc + 1, (kc + 1) & 1)
        int bf = kc & 1;
        bf16x8 af[4], bfr[4];
        #pragma unroll
        for (int im = 0; im < 4; im++) {
            int row = wm * 64 + im * 16 + mcol;
            int sg = (quad + (row >> 1)) & 3;
            af[im] = *(const bf16x8*)(&As[bf][row * 32 + sg * 8]);
        }
        #pragma unroll
        for (int jn = 0; jn < 4; jn++) {
            int row = wn * 64 + jn * 16 + mcol;
            int sg = (quad + (row >> 1)) & 3;
            bfr[jn] = *(const bf16x8*)(&Bs[bf][row * 32 + sg * 8]);
        }
        #pragma unroll
        for (int im = 0; im < 4; im++)
            #pragma unroll
            for (int jn = 0; jn < 4; jn++)
                acc[im][jn] = __builtin_amdgcn_mfma_f32_16x16x32_bf16(
                    af[im], bfr[jn], acc[im][jn], 0, 0, 0);
    }

    // epilogue: row = wm*64+im*16+quad*4+r, col = n0+wn*64+jn*16+mcol
    float bc[4];
    #pragma unroll
    for (int jn = 0; jn < 4; jn++) {
        int col = n0 + wn * 64 + jn * 16 + mcol;
        bc[jn] = bias[s * DM + col] + id_emb[s * DM + col];
    }
    #pragma unroll
    for (int im = 0; im < 4; im++) {
        #pragma unroll
        for (int r = 0; r < 4; r++) {
            int rowT = wm * 64 + im * 16 + quad * 4 + r;
            if (rowT >= rowsValid) continue;
            int t = toks[rowT];
            int p = pos[t];
            int ro = role[t];
            int b = t >> 11, l = t & 2047;
            size_t orow = (size_t)(b * LOUT + l + 1) * DM;
            const u16* prow = Pb + (size_t)p * DM;
            #pragma unroll
            for (int jn = 0; jn < 4; jn++) {
                int col = n0 + wn * 64 + jn * 16 + mcol;
                float val = acc[im][jn][r] + bc[jn]
                    + bf2f(prow[col])
                    + role_emb[ro * DM + col];
                out[orow + col] = val;
            }
        }
    }
#undef STAGE
}

// ---------------- Elementwise: unmasked rows (wave/token), CLS, attn ---------
__global__ __launch_bounds__(256) void ew_kernel(
    const int* __restrict__ pos, const int* __restrict__ sid,
    const int* __restrict__ role,
    const float* __restrict__ cls, const float* __restrict__ pos_emb,
    const float* __restrict__ id_emb, const float* __restrict__ role_emb,
    const int* __restrict__ wsi, float* __restrict__ out) {
    int bi = blockIdx.x;
    int tid = threadIdx.x;
    int lane = tid & 63;
    int wv = tid >> 6;
    if (bi < NTOK / 4) {
        int t = bi * 4 + wv;
        if (wsi[WS_MASK + t]) return;   // projected rows written by GEMM
        int p = pos[t], sd = sid[t], ro = role[t];
        int b = t >> 11, l = t & 2047;
        size_t orow = (size_t)(b * LOUT + l + 1) * DM;
        #pragma unroll
        for (int it = 0; it < 4; it++) {
            int c = it * 256 + lane * 4;
            float4 a = *(const float4*)(pos_emb + (size_t)p * DM + c);
            float4 d = *(const float4*)(id_emb + (size_t)sd * DM + c);
            float4 e = *(const float4*)(role_emb + (size_t)ro * DM + c);
            float4 o;
            o.x = a.x + d.x + e.x;
            o.y = a.y + d.y + e.y;
            o.z = a.z + d.z + e.z;
            o.w = a.w + d.w + e.w;
            *(float4*)(out + orow + c) = o;
        }
    } else if (bi < NTOK / 4 + 2) {
        int b = (bi - NTOK / 4) * 4 + wv;   // 8 CLS rows over 2 blocks
        size_t orow = (size_t)(b * LOUT) * DM;
        #pragma unroll
        for (int it = 0; it < 4; it++) {
            int c = it * 256 + lane * 4;
            float4 cc = *(const float4*)(cls + c);
            float4 a = *(const float4*)(pos_emb + c);            // pos row 0
            float4 d = *(const float4*)(id_emb + NS * DM + c);   // id row 16
            float4 e = *(const float4*)(role_emb + 2 * DM + c);  // role 2
            float4 o;
            o.x = cc.x + a.x + d.x + e.x;
            o.y = cc.y + a.y + d.y + e.y;
            o.z = cc.z + a.z + d.z + e.z;
            o.w = cc.w + a.w + d.w + e.w;
            *(float4*)(out + orow + c) = o;
        }
    } else {
        int i = (bi - NTOK / 4 - 2) * 256 + tid;
        if (i < ATTN_OUT) {
            int b = i / LOUT;
            int j = i - b * LOUT;
            float val = (j == 0) ? 1.0f : (float)wsi[WS_MASK + b * L_ + j - 1];
            out[TOK_OUT + i] = val;
        }
    }
}

extern "C" void kernel_launch(void* const* d_in, const int* in_sizes, int n_in,
                              void* d_out, int out_size, void* d_ws, size_t ws_size,
                              hipStream_t stream) {
    const float* emb = (const float*)d_in[0];
    const int* pos = (const int*)d_in[1];
    const int* sid = (const int*)d_in[2];
    const int* role = (const int*)d_in[3];
    const unsigned char* mask = (const unsigned char*)d_in[4];
    const float* W = (const float*)d_in[5];
    const float* bias = (const float*)d_in[6];
    const float* cls = (const float*)d_in[7];
    const float* pos_emb = (const float*)d_in[8];
    const float* id_emb = (const float*)d_in[9];
    const float* role_emb = (const float*)d_in[10];
    float* out = (float*)d_out;
    int* wsi = (int*)d_ws;
    unsigned char* wsb = (unsigned char*)d_ws;

    hipMemsetAsync(wsi, 0, 64 * sizeof(int), stream);
    hipLaunchKernelGGL(sort_kernel, dim3(64), dim3(256), 0, stream, mask, sid, wsi);
    hipLaunchKernelGGL(prep_kernel, dim3(4608 + 4096 + 4097), dim3(256), 0, stream,
                       emb, W, pos_emb, wsi, wsb);
    hipLaunchKernelGGL(gemm_big, dim3(576), dim3(512), 0, stream,
                       pos, role, bias, id_emb, role_emb, wsi, wsb, out);
    hipLaunchKernelGGL(ew_kernel, dim3(NTOK / 4 + 2 + 65), dim3(256), 0, stream,
                       pos, sid, role, cls, pos_emb, id_emb, role_emb, wsi, out);
}